// Round 2
// baseline (3725.611 us; speedup 1.0000x reference)
//
#include <hip/hip_runtime.h>
#include <cstdint>
#include <cstddef>

// Problem constants (from setup_inputs): B=64, T=2048, D=128, K=1024
#define DECAYF 0.99f
#define OMDF   0.01f   // 1 - DECAY
#define EPSF   1e-5f

constexpr int N_ROWS = 64 * 2048;   // 131072
constexpr int D      = 128;
constexpr int K      = 1024;

// ---------------------------------------------------------------------------
// K0: cnorm[k] = ||embed[k]||^2
// ---------------------------------------------------------------------------
__global__ __launch_bounds__(256) void cnorm_kernel(const float* __restrict__ embed,
                                                    float* __restrict__ cnorm) {
    int k = blockIdx.x * 256 + threadIdx.x;
    if (k >= K) return;
    const float4* e4 = (const float4*)(embed + (size_t)k * D);
    float a0 = 0.f, a1 = 0.f, a2 = 0.f, a3 = 0.f;
#pragma unroll
    for (int i = 0; i < D / 4; ++i) {
        float4 v = e4[i];
        a0 += v.x * v.x; a1 += v.y * v.y; a2 += v.z * v.z; a3 += v.w * v.w;
    }
    cnorm[k] = (a0 + a1) + (a2 + a3);
}

// ---------------------------------------------------------------------------
// K1: per-row argmax over codes + scatter-add epilogue.
// One thread per row; x row held in 128 VGPRs; embed row accessed with a
// wave-uniform index (k, i constants) -> scalar loads (SMEM), so the inner
// loop is pure v_fmac_f32 with 4 independent accumulator chains.
// ---------------------------------------------------------------------------
__global__ __launch_bounds__(256) void dist_kernel(const float* __restrict__ x,
                                                   const float* __restrict__ embed,
                                                   const float* __restrict__ cnorm,
                                                   float* __restrict__ out_idx,
                                                   float* __restrict__ counts,
                                                   float* __restrict__ embed_sum) {
    const int row = blockIdx.x * 256 + threadIdx.x;   // N_ROWS divisible by 256
    const float4* xp = (const float4*)(x + (size_t)row * D);
    float4 xr[32];
#pragma unroll
    for (int i = 0; i < 32; ++i) xr[i] = xp[i];

    // ||x||^2 (reference includes it: dist = -xn + 2*dot - cn; the constant
    // matters only through fp32 rounding of the sum, which we replicate).
    float xn;
    {
        float a0 = 0.f, a1 = 0.f, a2 = 0.f, a3 = 0.f;
#pragma unroll
        for (int i = 0; i < 32; ++i) {
            a0 += xr[i].x * xr[i].x; a1 += xr[i].y * xr[i].y;
            a2 += xr[i].z * xr[i].z; a3 += xr[i].w * xr[i].w;
        }
        xn = (a0 + a1) + (a2 + a3);
    }

    float best = -3.4e38f;
    int bidx = 0;
    const float4* e4all = (const float4*)embed;
    for (int k = 0; k < K; ++k) {
        const float4* ek = e4all + (size_t)k * (D / 4);
        float a0 = 0.f, a1 = 0.f, a2 = 0.f, a3 = 0.f;
#pragma unroll
        for (int i = 0; i < 32; ++i) {
            float4 e = ek[i];
            a0 += xr[i].x * e.x;
            a1 += xr[i].y * e.y;
            a2 += xr[i].z * e.z;
            a3 += xr[i].w * e.w;
        }
        float dot = (a0 + a1) + (a2 + a3);
        float s = (-xn + 2.0f * dot) - cnorm[k];
        if (s > best) { best = s; bidx = k; }   // strict > : first max wins (jnp.argmax)
    }

    out_idx[row] = (float)bidx;   // harness reads whole d_out as fp32

    // EMA scatter contributions (device-scope atomics)
    atomicAdd(counts + bidx, 1.0f);
    float* es = embed_sum + (size_t)bidx * D;
#pragma unroll
    for (int i = 0; i < 32; ++i) {
        atomicAdd(es + 4 * i + 0, xr[i].x);
        atomicAdd(es + 4 * i + 1, xr[i].y);
        atomicAdd(es + 4 * i + 2, xr[i].z);
        atomicAdd(es + 4 * i + 3, xr[i].w);
    }
}

// ---------------------------------------------------------------------------
// K2: quantized[row] = embed[idx[row]]  (coalesced writes; embed is L2-hot)
// ---------------------------------------------------------------------------
__global__ __launch_bounds__(256) void gather_kernel(const float* __restrict__ embed,
                                                     const float* __restrict__ out_idx,
                                                     float* __restrict__ quant) {
    int t = blockIdx.x * 256 + threadIdx.x;   // N_ROWS*32 threads, one float4 each
    int row = t >> 5;
    int j = t & 31;
    int k = (int)out_idx[row];
    ((float4*)quant)[(size_t)row * 32 + j] = ((const float4*)embed)[(size_t)k * 32 + j];
}

// ---------------------------------------------------------------------------
// K3: new_cluster_size + total + laplace-smoothed denominator (1 block)
// ---------------------------------------------------------------------------
__global__ __launch_bounds__(1024) void cluster_kernel(const float* __restrict__ cluster_size,
                                                       const float* __restrict__ counts,
                                                       float* __restrict__ out_ncs,
                                                       float* __restrict__ smoothed) {
    __shared__ float red[16];
    __shared__ float total_s;
    int k = threadIdx.x;   // 1024 threads == K
    float ncs = cluster_size[k] * DECAYF + OMDF * counts[k];
    out_ncs[k] = ncs;

    float v = ncs;
#pragma unroll
    for (int off = 32; off >= 1; off >>= 1) v += __shfl_down(v, off, 64);
    if ((k & 63) == 0) red[k >> 6] = v;
    __syncthreads();
    if (k < 16) {
        float t = red[k];
#pragma unroll
        for (int off = 8; off >= 1; off >>= 1) t += __shfl_down(t, off, 16);
        if (k == 0) total_s = t;
    }
    __syncthreads();
    float total = total_s;
    smoothed[k] = (ncs + EPSF) / (total + (float)K * EPSF) * total;
}

// ---------------------------------------------------------------------------
// K4: new_embed_avg = ea*0.99 + 0.01*embed_sum ; new_embed = nea / smoothed[k]
// ---------------------------------------------------------------------------
__global__ __launch_bounds__(256) void embed_update_kernel(const float* __restrict__ embed_avg,
                                                           const float* __restrict__ embed_sum,
                                                           const float* __restrict__ smoothed,
                                                           float* __restrict__ out_nea,
                                                           float* __restrict__ out_ne) {
    int t = blockIdx.x * 256 + threadIdx.x;   // K*D/4 threads
    float4 ea = ((const float4*)embed_avg)[t];
    float4 es = ((const float4*)embed_sum)[t];
    float sm = smoothed[t >> 5];
    float4 nea;
    nea.x = ea.x * DECAYF + OMDF * es.x;
    nea.y = ea.y * DECAYF + OMDF * es.y;
    nea.z = ea.z * DECAYF + OMDF * es.z;
    nea.w = ea.w * DECAYF + OMDF * es.w;
    ((float4*)out_nea)[t] = nea;
    float4 ne;
    ne.x = nea.x / sm; ne.y = nea.y / sm; ne.z = nea.z / sm; ne.w = nea.w / sm;
    ((float4*)out_ne)[t] = ne;
}

// ---------------------------------------------------------------------------
extern "C" void kernel_launch(void* const* d_in, const int* in_sizes, int n_in,
                              void* d_out, int out_size, void* d_ws, size_t ws_size,
                              hipStream_t stream) {
    const float* x            = (const float*)d_in[0];   // [N, D]
    const float* embed        = (const float*)d_in[1];   // [K, D]
    const float* embed_avg    = (const float*)d_in[2];   // [K, D]
    const float* cluster_size = (const float*)d_in[3];   // [K]

    // Output layout (flat fp32, reference return order):
    // quantized [N*D] | embed_ind [N] | new_embed [K*D] | new_cluster [K] | new_embed_avg [K*D]
    float* out       = (float*)d_out;
    float* out_quant = out;
    float* out_idx   = out_quant + (size_t)N_ROWS * D;
    float* out_ne    = out_idx + N_ROWS;
    float* out_ncs   = out_ne + (size_t)K * D;
    float* out_nea   = out_ncs + K;

    // Workspace: counts[K] | embed_sum[K*D] | cnorm[K] | smoothed[K]  (~525 KB)
    float* ws        = (float*)d_ws;
    float* counts    = ws;
    float* embed_sum = counts + K;
    float* cnorm     = embed_sum + (size_t)K * D;
    float* smoothed  = cnorm + K;

    // zero the atomic accumulation regions (ws is poisoned before every call)
    hipMemsetAsync(counts, 0, (size_t)(K + K * D) * sizeof(float), stream);

    cnorm_kernel<<<(K + 255) / 256, 256, 0, stream>>>(embed, cnorm);
    dist_kernel<<<N_ROWS / 256, 256, 0, stream>>>(x, embed, cnorm, out_idx, counts, embed_sum);
    gather_kernel<<<(N_ROWS * 32) / 256, 256, 0, stream>>>(embed, out_idx, out_quant);
    cluster_kernel<<<1, 1024, 0, stream>>>(cluster_size, counts, out_ncs, smoothed);
    embed_update_kernel<<<(K * D / 4) / 256, 256, 0, stream>>>(embed_avg, embed_sum, smoothed,
                                                               out_nea, out_ne);
}

// Round 3
// 1240.983 us; speedup vs baseline: 3.0021x; 3.0021x over previous
//
#include <hip/hip_runtime.h>
#include <cstdint>
#include <cstddef>

#define DECAYF 0.99f
#define OMDF   0.01f
#define EPSF   1e-5f

constexpr int N_ROWS = 64 * 2048;   // 131072
constexpr int D      = 128;
constexpr int K      = 1024;

// ---------------------------------------------------------------------------
// K0: cnorm[k] = ||embed[k]||^2  (fp32, 4-chain like reference-ish)
// ---------------------------------------------------------------------------
__global__ __launch_bounds__(256) void cnorm_kernel(const float* __restrict__ embed,
                                                    float* __restrict__ cnorm) {
    int k = blockIdx.x * 256 + threadIdx.x;
    if (k >= K) return;
    const float4* e4 = (const float4*)(embed + (size_t)k * D);
    float a0 = 0.f, a1 = 0.f, a2 = 0.f, a3 = 0.f;
#pragma unroll
    for (int i = 0; i < D / 4; ++i) {
        float4 v = e4[i];
        a0 += v.x * v.x; a1 += v.y * v.y; a2 += v.z * v.z; a3 += v.w * v.w;
    }
    cnorm[k] = (a0 + a1) + (a2 + a3);
}

// ---------------------------------------------------------------------------
// K1: tiled distance + argmax.
// Block: 256 threads, BM=64 rows x (16 tiles of BN=64 codes).
// Thread (tx=tid&15, ty=tid>>4): rows {ty+16r}, codes {tilebase+tx+16c}.
// LDS: xs[64][132], es[64][132] (pad +4 floats -> <=2-way bank aliasing).
// 2 blocks/CU (135 KB LDS). Compute floor: 1.72e10 FMA -> ~219 us.
// ---------------------------------------------------------------------------
__global__ __launch_bounds__(256, 2) void dist_tiled(const float* __restrict__ x,
                                                     const float* __restrict__ embed,
                                                     const float* __restrict__ cnorm,
                                                     float* __restrict__ out_idx,
                                                     int* __restrict__ idx_i32,
                                                     int* __restrict__ counts_i) {
    __shared__ float xs[64][132];
    __shared__ float es[64][132];

    const int tid = threadIdx.x;
    const int tx = tid & 15;
    const int ty = tid >> 4;
    const int rowbase = blockIdx.x * 64;

    // stage x tile: 64 rows * 32 float4 = 2048 float4, 8 per thread, coalesced
    {
        const float4* x4 = (const float4*)x;
        const size_t base4 = (size_t)rowbase * 32;
#pragma unroll
        for (int it = 0; it < 8; ++it) {
            int idx = it * 256 + tid;
            int row = idx >> 5, c4 = idx & 31;
            float4 v = x4[base4 + idx];
            *(float4*)&xs[row][c4 * 4] = v;
        }
    }
    __syncthreads();

    // ||x||^2 for this thread's 4 rows (reads broadcast across tx)
    float xn[4];
#pragma unroll
    for (int r = 0; r < 4; ++r) {
        const float* xrow = &xs[ty + 16 * r][0];
        float a0 = 0.f, a1 = 0.f, a2 = 0.f, a3 = 0.f;
#pragma unroll 8
        for (int i = 0; i < 32; ++i) {
            float4 v = *(const float4*)&xrow[4 * i];
            a0 += v.x * v.x; a1 += v.y * v.y; a2 += v.z * v.z; a3 += v.w * v.w;
        }
        xn[r] = (a0 + a1) + (a2 + a3);
    }

    float best[4];
    int bidx[4];
#pragma unroll
    for (int r = 0; r < 4; ++r) { best[r] = -3.4e38f; bidx[r] = 0; }

    const float4* e4 = (const float4*)embed;
    for (int t = 0; t < 16; ++t) {
        __syncthreads();   // protect es against WAR from previous tile
        {
            const size_t base4 = (size_t)t * 64 * 32;
#pragma unroll
            for (int it = 0; it < 8; ++it) {
                int idx = it * 256 + tid;
                int row = idx >> 5, c4 = idx & 31;
                float4 v = e4[base4 + idx];
                *(float4*)&es[row][c4 * 4] = v;
            }
        }
        // hoist cnorm loads for this tile (hide latency under barrier+compute)
        float cn[4];
#pragma unroll
        for (int c = 0; c < 4; ++c) cn[c] = cnorm[t * 64 + tx + 16 * c];
        __syncthreads();

        float acc[4][4];
#pragma unroll
        for (int r = 0; r < 4; ++r)
#pragma unroll
            for (int c = 0; c < 4; ++c) acc[r][c] = 0.f;

#pragma unroll 8
        for (int d4 = 0; d4 < 32; ++d4) {
            float4 a[4], b[4];
#pragma unroll
            for (int r = 0; r < 4; ++r) a[r] = *(const float4*)&xs[ty + 16 * r][4 * d4];
#pragma unroll
            for (int c = 0; c < 4; ++c) b[c] = *(const float4*)&es[tx + 16 * c][4 * d4];
#pragma unroll
            for (int r = 0; r < 4; ++r)
#pragma unroll
                for (int c = 0; c < 4; ++c) {
                    acc[r][c] = fmaf(a[r].x, b[c].x, acc[r][c]);
                    acc[r][c] = fmaf(a[r].y, b[c].y, acc[r][c]);
                    acc[r][c] = fmaf(a[r].z, b[c].z, acc[r][c]);
                    acc[r][c] = fmaf(a[r].w, b[c].w, acc[r][c]);
                }
        }

#pragma unroll
        for (int r = 0; r < 4; ++r)
#pragma unroll
            for (int c = 0; c < 4; ++c) {
                float s = (-xn[r] + 2.0f * acc[r][c]) - cn[c];
                if (s > best[r]) { best[r] = s; bidx[r] = t * 64 + tx + 16 * c; }
            }
    }

    // cross-thread argmax reduce: 16 tx candidates per row, lowest-index ties
    __syncthreads();
    float* sbest = &es[0][0];
    int*   sidx  = (int*)&xs[0][0];
#pragma unroll
    for (int r = 0; r < 4; ++r) {
        int row = ty + 16 * r;
        sbest[row * 16 + tx] = best[r];
        sidx[row * 16 + tx] = bidx[r];
    }
    __syncthreads();
    if (tid < 64) {
        int row = tid;
        float bs = sbest[row * 16];
        int bi = sidx[row * 16];
#pragma unroll
        for (int j = 1; j < 16; ++j) {
            float s = sbest[row * 16 + j];
            int id = sidx[row * 16 + j];
            if (s > bs || (s == bs && id < bi)) { bs = s; bi = id; }
        }
        int grow = rowbase + row;
        out_idx[grow] = (float)bi;
        idx_i32[grow] = bi;
        atomicAdd(&counts_i[bi], 1);
    }
}

// ---------------------------------------------------------------------------
// K2: scan counts -> offsets/cursor; ncs, total, smoothed (1 block, 1024 thr)
// ---------------------------------------------------------------------------
__global__ __launch_bounds__(1024) void scan_cluster_kernel(const int* __restrict__ counts_i,
                                                            const float* __restrict__ cluster_size,
                                                            int* __restrict__ offsets,
                                                            int* __restrict__ cursor,
                                                            float* __restrict__ out_ncs,
                                                            float* __restrict__ smoothed) {
    __shared__ int s[1024];
    __shared__ float red[16];
    __shared__ float total_s;
    int k = threadIdx.x;
    int c = counts_i[k];
    s[k] = c;
    __syncthreads();
    for (int off = 1; off < 1024; off <<= 1) {
        int v = (k >= off) ? s[k - off] : 0;
        __syncthreads();
        s[k] += v;
        __syncthreads();
    }
    int offx = s[k] - c;   // exclusive
    offsets[k] = offx;
    cursor[k] = offx;

    float ncs = cluster_size[k] * DECAYF + OMDF * (float)c;
    out_ncs[k] = ncs;

    float v = ncs;
#pragma unroll
    for (int off = 32; off >= 1; off >>= 1) v += __shfl_down(v, off, 64);
    if ((k & 63) == 0) red[k >> 6] = v;
    __syncthreads();
    if (k < 16) {
        float t = red[k];
#pragma unroll
        for (int off = 8; off >= 1; off >>= 1) t += __shfl_down(t, off, 16);
        if (k == 0) total_s = t;
    }
    __syncthreads();
    float total = total_s;
    smoothed[k] = (ncs + EPSF) / (total + (float)K * EPSF) * total;
}

// ---------------------------------------------------------------------------
// K3: scatter row ids into per-code segments
// ---------------------------------------------------------------------------
__global__ __launch_bounds__(256) void scatter_kernel(const int* __restrict__ idx_i32,
                                                      int* __restrict__ cursor,
                                                      int* __restrict__ rowlist) {
    int row = blockIdx.x * 256 + threadIdx.x;
    int code = idx_i32[row];
    int pos = atomicAdd(&cursor[code], 1);
    rowlist[pos] = row;
}

// ---------------------------------------------------------------------------
// K4: per-code segmented sum of x rows + EMA + normalize (block = code)
// ---------------------------------------------------------------------------
__global__ __launch_bounds__(128) void segsum_update_kernel(const float* __restrict__ x,
                                                            const int* __restrict__ offsets,
                                                            const int* __restrict__ counts_i,
                                                            const int* __restrict__ rowlist,
                                                            const float* __restrict__ embed_avg,
                                                            const float* __restrict__ smoothed,
                                                            float* __restrict__ out_nea,
                                                            float* __restrict__ out_ne) {
    int k = blockIdx.x;
    int d = threadIdx.x;
    int start = offsets[k];
    int cnt = counts_i[k];
    float a0 = 0.f, a1 = 0.f, a2 = 0.f, a3 = 0.f;
    int i = 0;
    for (; i + 4 <= cnt; i += 4) {
        int r0 = rowlist[start + i + 0];
        int r1 = rowlist[start + i + 1];
        int r2 = rowlist[start + i + 2];
        int r3 = rowlist[start + i + 3];
        a0 += x[(size_t)r0 * D + d];
        a1 += x[(size_t)r1 * D + d];
        a2 += x[(size_t)r2 * D + d];
        a3 += x[(size_t)r3 * D + d];
    }
    for (; i < cnt; ++i) a0 += x[(size_t)rowlist[start + i] * D + d];
    float esum = (a0 + a1) + (a2 + a3);
    float nea = embed_avg[(size_t)k * D + d] * DECAYF + OMDF * esum;
    out_nea[(size_t)k * D + d] = nea;
    out_ne[(size_t)k * D + d] = nea / smoothed[k];
}

// ---------------------------------------------------------------------------
// K5: quantized[row] = embed[idx[row]]
// ---------------------------------------------------------------------------
__global__ __launch_bounds__(256) void gather_kernel(const float* __restrict__ embed,
                                                     const int* __restrict__ idx_i32,
                                                     float* __restrict__ quant) {
    int t = blockIdx.x * 256 + threadIdx.x;
    int row = t >> 5;
    int j = t & 31;
    int k = idx_i32[row];
    ((float4*)quant)[(size_t)row * 32 + j] = ((const float4*)embed)[(size_t)k * 32 + j];
}

// ---------------------------------------------------------------------------
extern "C" void kernel_launch(void* const* d_in, const int* in_sizes, int n_in,
                              void* d_out, int out_size, void* d_ws, size_t ws_size,
                              hipStream_t stream) {
    const float* x            = (const float*)d_in[0];
    const float* embed        = (const float*)d_in[1];
    const float* embed_avg    = (const float*)d_in[2];
    const float* cluster_size = (const float*)d_in[3];

    float* out       = (float*)d_out;
    float* out_quant = out;
    float* out_idx   = out_quant + (size_t)N_ROWS * D;
    float* out_ne    = out_idx + N_ROWS;
    float* out_ncs   = out_ne + (size_t)K * D;
    float* out_nea   = out_ncs + K;

    // workspace layout (4-byte units)
    int*   counts_i = (int*)d_ws;                 // K
    int*   offsets  = counts_i + K;               // K
    int*   cursor   = offsets + K;                // K
    int*   idx_i32  = cursor + K;                 // N
    int*   rowlist  = idx_i32 + N_ROWS;           // N
    float* cnorm    = (float*)(rowlist + N_ROWS); // K
    float* smoothed = cnorm + K;                  // K  (total ~1.06 MB)

    hipMemsetAsync(counts_i, 0, K * sizeof(int), stream);

    cnorm_kernel<<<(K + 255) / 256, 256, 0, stream>>>(embed, cnorm);
    dist_tiled<<<N_ROWS / 64, 256, 0, stream>>>(x, embed, cnorm, out_idx, idx_i32, counts_i);
    scan_cluster_kernel<<<1, 1024, 0, stream>>>(counts_i, cluster_size, offsets, cursor,
                                                out_ncs, smoothed);
    scatter_kernel<<<N_ROWS / 256, 256, 0, stream>>>(idx_i32, cursor, rowlist);
    segsum_update_kernel<<<K, 128, 0, stream>>>(x, offsets, counts_i, rowlist,
                                                embed_avg, smoothed, out_nea, out_ne);
    gather_kernel<<<(N_ROWS * 32) / 256, 256, 0, stream>>>(embed, idx_i32, out_quant);
}

// Round 4
// 1057.890 us; speedup vs baseline: 3.5217x; 1.1731x over previous
//
#include <hip/hip_runtime.h>
#include <cstdint>
#include <cstddef>

#define DECAYF 0.99f
#define OMDF   0.01f
#define EPSF   1e-5f

constexpr int N_ROWS = 64 * 2048;   // 131072
constexpr int D      = 128;
constexpr int K      = 1024;

// ---------------------------------------------------------------------------
// K0: cnorm[k] = ||embed[k]||^2
// ---------------------------------------------------------------------------
__global__ __launch_bounds__(256) void cnorm_kernel(const float* __restrict__ embed,
                                                    float* __restrict__ cnorm) {
    int k = blockIdx.x * 256 + threadIdx.x;
    if (k >= K) return;
    const float4* e4 = (const float4*)(embed + (size_t)k * D);
    float a0 = 0.f, a1 = 0.f, a2 = 0.f, a3 = 0.f;
#pragma unroll
    for (int i = 0; i < D / 4; ++i) {
        float4 v = e4[i];
        a0 += v.x * v.x; a1 += v.y * v.y; a2 += v.z * v.z; a3 += v.w * v.w;
    }
    cnorm[k] = (a0 + a1) + (a2 + a3);
}

// ---------------------------------------------------------------------------
// K1: tiled distance + argmax.
// Block: 256 threads (tx=tid&15 codes, ty=tid>>4 rows), 8x8 micro-tile:
//   rows ty+16r (r<8), codes tx+16c (c<8) -> 128x128 block tile.
// Per d4-iter: 16 ds_read_b128 per 256 FMA = 1 B/FMA -> LDS demand ~= peak,
// VALU becomes the binding pipe (round-3 was 2 B/FMA -> LDS-bound at 65%).
// LDS 2x67.6 KB = 135 KB -> 1 block/CU (4 waves); ILP from 64 accumulators.
// Score uses 2*dot - cn (dropping -||x||^2 is argmax-invariant).
// ---------------------------------------------------------------------------
__global__ __launch_bounds__(256, 1) void dist_tiled(const float* __restrict__ x,
                                                     const float* __restrict__ embed,
                                                     const float* __restrict__ cnorm,
                                                     float* __restrict__ out_idx,
                                                     int* __restrict__ idx_i32,
                                                     int* __restrict__ counts_i) {
    __shared__ float xs[128][132];
    __shared__ float es[128][132];

    const int tid = threadIdx.x;
    const int tx = tid & 15;
    const int ty = tid >> 4;
    const int rowbase = blockIdx.x * 128;

    // stage x tile: 128 rows * 32 float4 = 4096 float4, 16 per thread, coalesced
    {
        const float4* x4 = (const float4*)x;
        const size_t base4 = (size_t)rowbase * 32;
#pragma unroll
        for (int it = 0; it < 16; ++it) {
            int idx = it * 256 + tid;
            int row = idx >> 5, c4 = idx & 31;
            float4 v = x4[base4 + idx];
            *(float4*)&xs[row][c4 * 4] = v;
        }
    }

    float best[8];
    int bidx[8];
#pragma unroll
    for (int r = 0; r < 8; ++r) { best[r] = -3.4e38f; bidx[r] = 0; }

    const float4* e4 = (const float4*)embed;
    for (int t = 0; t < 8; ++t) {
        __syncthreads();   // WAR protect es (and covers initial xs stage at t=0)
        {
            const size_t base4 = (size_t)t * 128 * 32;
#pragma unroll
            for (int it = 0; it < 16; ++it) {
                int idx = it * 256 + tid;
                int row = idx >> 5, c4 = idx & 31;
                float4 v = e4[base4 + idx];
                *(float4*)&es[row][c4 * 4] = v;
            }
        }
        float cn[8];
#pragma unroll
        for (int c = 0; c < 8; ++c) cn[c] = cnorm[t * 128 + tx + 16 * c];
        __syncthreads();

        float acc[8][8];
#pragma unroll
        for (int r = 0; r < 8; ++r)
#pragma unroll
            for (int c = 0; c < 8; ++c) acc[r][c] = 0.f;

#pragma unroll 2
        for (int d4 = 0; d4 < 32; ++d4) {
            float4 a[8], b[8];
#pragma unroll
            for (int r = 0; r < 8; ++r) a[r] = *(const float4*)&xs[ty + 16 * r][4 * d4];
#pragma unroll
            for (int c = 0; c < 8; ++c) b[c] = *(const float4*)&es[tx + 16 * c][4 * d4];
#pragma unroll
            for (int r = 0; r < 8; ++r)
#pragma unroll
                for (int c = 0; c < 8; ++c) {
                    acc[r][c] = fmaf(a[r].x, b[c].x, acc[r][c]);
                    acc[r][c] = fmaf(a[r].y, b[c].y, acc[r][c]);
                    acc[r][c] = fmaf(a[r].z, b[c].z, acc[r][c]);
                    acc[r][c] = fmaf(a[r].w, b[c].w, acc[r][c]);
                }
        }

#pragma unroll
        for (int r = 0; r < 8; ++r)
#pragma unroll
            for (int c = 0; c < 8; ++c) {
                float s = 2.0f * acc[r][c] - cn[c];
                if (s > best[r]) { best[r] = s; bidx[r] = t * 128 + tx + 16 * c; }
            }
    }

    // cross-thread argmax reduce: 16 tx candidates per row, 128 rows
    __syncthreads();
    float* sbest = &es[0][0];
    int*   sidx  = (int*)&xs[0][0];
#pragma unroll
    for (int r = 0; r < 8; ++r) {
        int row = ty + 16 * r;
        sbest[row * 16 + tx] = best[r];
        sidx[row * 16 + tx] = bidx[r];
    }
    __syncthreads();
    if (tid < 128) {
        int row = tid;
        float bs = sbest[row * 16];
        int bi = sidx[row * 16];
#pragma unroll
        for (int j = 1; j < 16; ++j) {
            float s = sbest[row * 16 + j];
            int id = sidx[row * 16 + j];
            if (s > bs || (s == bs && id < bi)) { bs = s; bi = id; }
        }
        int grow = rowbase + row;
        out_idx[grow] = (float)bi;
        idx_i32[grow] = bi;
        atomicAdd(&counts_i[bi], 1);
    }
}

// ---------------------------------------------------------------------------
// K2: ncs, total, smoothed (1 block, 1024 threads)
// ---------------------------------------------------------------------------
__global__ __launch_bounds__(1024) void cluster_kernel(const int* __restrict__ counts_i,
                                                       const float* __restrict__ cluster_size,
                                                       float* __restrict__ out_ncs,
                                                       float* __restrict__ smoothed) {
    __shared__ float red[16];
    __shared__ float total_s;
    int k = threadIdx.x;
    float ncs = cluster_size[k] * DECAYF + OMDF * (float)counts_i[k];
    out_ncs[k] = ncs;

    float v = ncs;
#pragma unroll
    for (int off = 32; off >= 1; off >>= 1) v += __shfl_down(v, off, 64);
    if ((k & 63) == 0) red[k >> 6] = v;
    __syncthreads();
    if (k < 16) {
        float t = red[k];
#pragma unroll
        for (int off = 8; off >= 1; off >>= 1) t += __shfl_down(t, off, 16);
        if (k == 0) total_s = t;
    }
    __syncthreads();
    float total = total_s;
    smoothed[k] = (ncs + EPSF) / (total + (float)K * EPSF) * total;
}

// ---------------------------------------------------------------------------
// K3: atomic-free segmented sum: block = code k; scan the full idx array
// (L2-resident, 512 KB) in chunks, queue matching rows in LDS, accumulate.
// Chunk size == queue capacity -> overflow impossible. Then EMA + normalize.
// ---------------------------------------------------------------------------
constexpr int CH = 8192;   // rows per chunk (= LDS queue capacity, 32 KB)

__global__ __launch_bounds__(128) void segsum_scan(const float* __restrict__ x,
                                                   const int* __restrict__ idx_i32,
                                                   const float* __restrict__ embed_avg,
                                                   const float* __restrict__ smoothed,
                                                   float* __restrict__ out_nea,
                                                   float* __restrict__ out_ne) {
    __shared__ int q[CH];
    __shared__ int qn;
    const int k = blockIdx.x;
    const int tid = threadIdx.x;   // == d
    float a0 = 0.f, a1 = 0.f, a2 = 0.f, a3 = 0.f;

    for (int base = 0; base < N_ROWS; base += CH) {
        if (tid == 0) qn = 0;
        __syncthreads();
#pragma unroll 4
        for (int i = 0; i < CH / 128; ++i) {
            int row = base + i * 128 + tid;
            if (idx_i32[row] == k) {
                int p = atomicAdd(&qn, 1);   // LDS-scope atomic
                q[p] = row;
            }
        }
        __syncthreads();
        int n = qn;
        int j = 0;
        for (; j + 4 <= n; j += 4) {
            a0 += x[(size_t)q[j + 0] * D + tid];
            a1 += x[(size_t)q[j + 1] * D + tid];
            a2 += x[(size_t)q[j + 2] * D + tid];
            a3 += x[(size_t)q[j + 3] * D + tid];
        }
        for (; j < n; ++j) a0 += x[(size_t)q[j] * D + tid];
        __syncthreads();   // WAR protect q/qn for next chunk
    }

    float esum = (a0 + a1) + (a2 + a3);
    float nea = embed_avg[(size_t)k * D + tid] * DECAYF + OMDF * esum;
    out_nea[(size_t)k * D + tid] = nea;
    out_ne[(size_t)k * D + tid] = nea / smoothed[k];
}

// ---------------------------------------------------------------------------
// K4: quantized[row] = embed[idx[row]]
// ---------------------------------------------------------------------------
__global__ __launch_bounds__(256) void gather_kernel(const float* __restrict__ embed,
                                                     const int* __restrict__ idx_i32,
                                                     float* __restrict__ quant) {
    int t = blockIdx.x * 256 + threadIdx.x;
    int row = t >> 5;
    int j = t & 31;
    int k = idx_i32[row];
    ((float4*)quant)[(size_t)row * 32 + j] = ((const float4*)embed)[(size_t)k * 32 + j];
}

// ---------------------------------------------------------------------------
extern "C" void kernel_launch(void* const* d_in, const int* in_sizes, int n_in,
                              void* d_out, int out_size, void* d_ws, size_t ws_size,
                              hipStream_t stream) {
    const float* x            = (const float*)d_in[0];
    const float* embed        = (const float*)d_in[1];
    const float* embed_avg    = (const float*)d_in[2];
    const float* cluster_size = (const float*)d_in[3];

    float* out       = (float*)d_out;
    float* out_quant = out;
    float* out_idx   = out_quant + (size_t)N_ROWS * D;
    float* out_ne    = out_idx + N_ROWS;
    float* out_ncs   = out_ne + (size_t)K * D;
    float* out_nea   = out_ncs + K;

    // workspace layout (4-byte units)
    int*   counts_i = (int*)d_ws;                  // K
    int*   idx_i32  = counts_i + K;                // N
    float* cnorm    = (float*)(idx_i32 + N_ROWS);  // K
    float* smoothed = cnorm + K;                   // K

    hipMemsetAsync(counts_i, 0, K * sizeof(int), stream);

    cnorm_kernel<<<(K + 255) / 256, 256, 0, stream>>>(embed, cnorm);
    dist_tiled<<<N_ROWS / 128, 256, 0, stream>>>(x, embed, cnorm, out_idx, idx_i32, counts_i);
    cluster_kernel<<<1, 1024, 0, stream>>>(counts_i, cluster_size, out_ncs, smoothed);
    segsum_scan<<<K, 128, 0, stream>>>(x, idx_i32, embed_avg, smoothed, out_nea, out_ne);
    gather_kernel<<<(N_ROWS * 32) / 256, 256, 0, stream>>>(embed, idx_i32, out_quant);
}

// Round 5
// 699.353 us; speedup vs baseline: 5.3272x; 1.5127x over previous
//
#include <hip/hip_runtime.h>
#include <cstdint>
#include <cstddef>

#define DECAYF 0.99f
#define OMDF   0.01f
#define EPSF   1e-5f
#define MARGIN 0.6f   // bf16 score-error 12-sigma bound; flagged rows get exact fp32 rescore

constexpr int N_ROWS = 64 * 2048;   // 131072
constexpr int D      = 128;
constexpr int K      = 1024;

typedef __attribute__((ext_vector_type(8))) short bf16x8;   // 8 bf16 = 4 VGPRs
typedef __attribute__((ext_vector_type(4))) float f32x4;

__device__ __forceinline__ unsigned short f2bf(float f) {
    unsigned u = __float_as_uint(f);
    u += 0x7FFFu + ((u >> 16) & 1u);   // RNE
    return (unsigned short)(u >> 16);
}

// ---------------------------------------------------------------------------
// Convert x fp32 -> bf16 (into the quantized region of d_out, overwritten last)
// ---------------------------------------------------------------------------
__global__ __launch_bounds__(256) void convert_x(const float* __restrict__ x,
                                                 unsigned short* __restrict__ xb) {
    int i = blockIdx.x * 256 + threadIdx.x;          // N*D/8 threads
    const float4* x4 = (const float4*)x;
    float4 a = x4[2 * i], b = x4[2 * i + 1];
    uint4 o;
    o.x = (unsigned)f2bf(a.x) | ((unsigned)f2bf(a.y) << 16);
    o.y = (unsigned)f2bf(a.z) | ((unsigned)f2bf(a.w) << 16);
    o.z = (unsigned)f2bf(b.x) | ((unsigned)f2bf(b.y) << 16);
    o.w = (unsigned)f2bf(b.z) | ((unsigned)f2bf(b.w) << 16);
    ((uint4*)xb)[i] = o;
}

__global__ __launch_bounds__(256) void convert_e(const float* __restrict__ e,
                                                 unsigned short* __restrict__ eb) {
    int i = blockIdx.x * 256 + threadIdx.x;          // K*D/8 threads
    const float4* e4 = (const float4*)e;
    float4 a = e4[2 * i], b = e4[2 * i + 1];
    uint4 o;
    o.x = (unsigned)f2bf(a.x) | ((unsigned)f2bf(a.y) << 16);
    o.y = (unsigned)f2bf(a.z) | ((unsigned)f2bf(a.w) << 16);
    o.z = (unsigned)f2bf(b.x) | ((unsigned)f2bf(b.y) << 16);
    o.w = (unsigned)f2bf(b.z) | ((unsigned)f2bf(b.w) << 16);
    ((uint4*)eb)[i] = o;
}

// ---------------------------------------------------------------------------
// cnorm[k] = ||embed[k]||^2 (fp32)
// ---------------------------------------------------------------------------
__global__ __launch_bounds__(256) void cnorm_kernel(const float* __restrict__ embed,
                                                    float* __restrict__ cnorm) {
    int k = blockIdx.x * 256 + threadIdx.x;
    if (k >= K) return;
    const float4* e4 = (const float4*)(embed + (size_t)k * D);
    float a0 = 0.f, a1 = 0.f, a2 = 0.f, a3 = 0.f;
#pragma unroll
    for (int i = 0; i < D / 4; ++i) {
        float4 v = e4[i];
        a0 += v.x * v.x; a1 += v.y * v.y; a2 += v.z * v.z; a3 += v.w * v.w;
    }
    cnorm[k] = (a0 + a1) + (a2 + a3);
}

// ---------------------------------------------------------------------------
// MFMA distance + approx argmax with best/best2 margin flagging.
// 16x16x32 bf16 NT-GEMM (verified layouts: A m=lane&15,k=quad*8+j; C col=lane&15,
// row=quad*4+reg). Wave owns 64 rows (4 C-tile sets sharing B-frags); block =
// 4 waves = 256 rows; grid 512. B-frags read direct from L1/L2 (embed_bf16
// 256 KB, hot). Flagged rows (b1-b2 < MARGIN) appended for exact rescore.
// ---------------------------------------------------------------------------
__global__ __launch_bounds__(256) void mfma_dist(const unsigned short* __restrict__ xb,
                                                 const unsigned short* __restrict__ eb,
                                                 const float* __restrict__ cnorm,
                                                 float* __restrict__ out_idx,
                                                 int* __restrict__ idx_i32,
                                                 int* __restrict__ flag_cnt,
                                                 int* __restrict__ flag_list) {
    __shared__ float sb1[256 * 16];
    __shared__ float sb2[256 * 16];
    __shared__ float sid[256 * 16];

    const int tid = threadIdx.x;
    const int wave = tid >> 6;
    const int lane = tid & 63;
    const int l15 = lane & 15;
    const int quad = lane >> 4;
    const int rowbase = blockIdx.x * 256 + wave * 64;

    // preload A-frags: 4 sets x 4 d-chunks, 16 B contiguous each
    bf16x8 a[4][4];
#pragma unroll
    for (int s = 0; s < 4; ++s) {
        int row = rowbase + s * 16 + l15;
#pragma unroll
        for (int c = 0; c < 4; ++c)
            a[s][c] = *(const bf16x8*)(xb + (size_t)row * D + c * 32 + quad * 8);
    }

    float b1[4][4], b2[4][4], idf[4][4];
#pragma unroll
    for (int s = 0; s < 4; ++s)
#pragma unroll
        for (int r = 0; r < 4; ++r) { b1[s][r] = -3.4e38f; b2[s][r] = -3.4e38f; idf[s][r] = 0.f; }

    for (int cb = 0; cb < K; cb += 16) {
        const int code = cb + l15;
        bf16x8 bfr[4];
#pragma unroll
        for (int c = 0; c < 4; ++c)
            bfr[c] = *(const bf16x8*)(eb + (size_t)code * D + c * 32 + quad * 8);
        const float cn = cnorm[code];
        const float colf = (float)code;

#pragma unroll
        for (int s = 0; s < 4; ++s) {
            f32x4 acc = {0.f, 0.f, 0.f, 0.f};
#pragma unroll
            for (int c = 0; c < 4; ++c)
                acc = __builtin_amdgcn_mfma_f32_16x16x32_bf16(a[s][c], bfr[c], acc, 0, 0, 0);
#pragma unroll
            for (int r = 0; r < 4; ++r) {
                float sc = 2.0f * acc[r] - cn;
                float old = b1[s][r];
                b1[s][r] = fmaxf(old, sc);
                b2[s][r] = fmaxf(fminf(sc, old), b2[s][r]);
                idf[s][r] = (sc > old) ? colf : idf[s][r];
            }
        }
    }

    // dump per-lane candidates: row lr has 16 candidates (one per l15)
#pragma unroll
    for (int s = 0; s < 4; ++s)
#pragma unroll
        for (int r = 0; r < 4; ++r) {
            int lr = wave * 64 + s * 16 + quad * 4 + r;
            sb1[lr * 16 + l15] = b1[s][r];
            sb2[lr * 16 + l15] = b2[s][r];
            sid[lr * 16 + l15] = idf[s][r];
        }
    __syncthreads();

    // one thread per row: merge 16 (b1,b2,idx) candidates
    {
        float bs = sb1[tid * 16], ss = sb2[tid * 16], bi = sid[tid * 16];
#pragma unroll
        for (int j = 1; j < 16; ++j) {
            float v = sb1[tid * 16 + j];
            float w = sb2[tid * 16 + j];
            float id = sid[tid * 16 + j];
            if (v > bs) { ss = fmaxf(bs, w); bi = id; bs = v; }
            else {
                ss = fmaxf(ss, v);
                if (v == bs && id < bi) bi = id;
            }
        }
        int grow = blockIdx.x * 256 + tid;
        out_idx[grow] = bi;
        idx_i32[grow] = (int)bi;
        if (bs - ss < MARGIN) {
            int p = atomicAdd(flag_cnt, 1);
            flag_list[p] = grow;
        }
    }
}

// ---------------------------------------------------------------------------
// Exact fp32 rescore of flagged rows (round-4 tiled structure + indirection).
// Grid-stride over 128-row chunks of flag_list; fixed 256-block launch.
// ---------------------------------------------------------------------------
__global__ __launch_bounds__(256, 1) void rescore(const float* __restrict__ x,
                                                  const float* __restrict__ embed,
                                                  const float* __restrict__ cnorm,
                                                  const int* __restrict__ flag_cnt,
                                                  const int* __restrict__ flag_list,
                                                  float* __restrict__ out_idx,
                                                  int* __restrict__ idx_i32) {
    __shared__ float xs[128][132];
    __shared__ float es[128][132];

    const int tid = threadIdx.x;
    const int tx = tid & 15;
    const int ty = tid >> 4;
    const int cnt = *flag_cnt;
    const int nch = (cnt + 127) >> 7;

    for (int ch = blockIdx.x; ch < nch; ch += gridDim.x) {
        __syncthreads();   // protect xs/es reuse across grid-stride iterations
        {
            const float4* x4 = (const float4*)x;
#pragma unroll
            for (int it = 0; it < 16; ++it) {
                int idx = it * 256 + tid;
                int slot = idx >> 5, c4 = idx & 31;
                int fi = ch * 128 + slot;
                int grow = flag_list[fi < cnt ? fi : cnt - 1];
                float4 v = x4[(size_t)grow * 32 + c4];
                *(float4*)&xs[slot][c4 * 4] = v;
            }
        }

        float best[8];
        int bidx[8];
#pragma unroll
        for (int r = 0; r < 8; ++r) { best[r] = -3.4e38f; bidx[r] = 0; }

        const float4* e4 = (const float4*)embed;
        for (int t = 0; t < 8; ++t) {
            __syncthreads();
            {
                const size_t base4 = (size_t)t * 128 * 32;
#pragma unroll
                for (int it = 0; it < 16; ++it) {
                    int idx = it * 256 + tid;
                    int row = idx >> 5, c4 = idx & 31;
                    float4 v = e4[base4 + idx];
                    *(float4*)&es[row][c4 * 4] = v;
                }
            }
            float cn[8];
#pragma unroll
            for (int c = 0; c < 8; ++c) cn[c] = cnorm[t * 128 + tx + 16 * c];
            __syncthreads();

            float acc[8][8];
#pragma unroll
            for (int r = 0; r < 8; ++r)
#pragma unroll
                for (int c = 0; c < 8; ++c) acc[r][c] = 0.f;

#pragma unroll 2
            for (int d4 = 0; d4 < 32; ++d4) {
                float4 av[8], bv[8];
#pragma unroll
                for (int r = 0; r < 8; ++r) av[r] = *(const float4*)&xs[ty + 16 * r][4 * d4];
#pragma unroll
                for (int c = 0; c < 8; ++c) bv[c] = *(const float4*)&es[tx + 16 * c][4 * d4];
#pragma unroll
                for (int r = 0; r < 8; ++r)
#pragma unroll
                    for (int c = 0; c < 8; ++c) {
                        acc[r][c] = fmaf(av[r].x, bv[c].x, acc[r][c]);
                        acc[r][c] = fmaf(av[r].y, bv[c].y, acc[r][c]);
                        acc[r][c] = fmaf(av[r].z, bv[c].z, acc[r][c]);
                        acc[r][c] = fmaf(av[r].w, bv[c].w, acc[r][c]);
                    }
            }

#pragma unroll
            for (int r = 0; r < 8; ++r)
#pragma unroll
                for (int c = 0; c < 8; ++c) {
                    float s = 2.0f * acc[r][c] - cn[c];
                    if (s > best[r]) { best[r] = s; bidx[r] = t * 128 + tx + 16 * c; }
                }
        }

        __syncthreads();
        float* sbest = &es[0][0];
        int*   sidx  = (int*)&xs[0][0];
#pragma unroll
        for (int r = 0; r < 8; ++r) {
            int row = ty + 16 * r;
            sbest[row * 16 + tx] = best[r];
            sidx[row * 16 + tx] = bidx[r];
        }
        __syncthreads();
        if (tid < 128) {
            float bs = sbest[tid * 16];
            int bi = sidx[tid * 16];
#pragma unroll
            for (int j = 1; j < 16; ++j) {
                float s = sbest[tid * 16 + j];
                int id = sidx[tid * 16 + j];
                if (s > bs || (s == bs && id < bi)) { bs = s; bi = id; }
            }
            int fi = ch * 128 + tid;
            if (fi < cnt) {
                int grow = flag_list[fi];
                out_idx[grow] = (float)bi;
                idx_i32[grow] = bi;
            }
        }
    }
}

// ---------------------------------------------------------------------------
// Histogram of final indices (LDS-privatized)
// ---------------------------------------------------------------------------
__global__ __launch_bounds__(256) void hist_kernel(const int* __restrict__ idx_i32,
                                                   int* __restrict__ counts_i) {
    __shared__ int h[K];
    for (int i = threadIdx.x; i < K; i += 256) h[i] = 0;
    __syncthreads();
    for (int row = blockIdx.x * 256 + threadIdx.x; row < N_ROWS; row += gridDim.x * 256)
        atomicAdd(&h[idx_i32[row]], 1);
    __syncthreads();
    for (int i = threadIdx.x; i < K; i += 256)
        if (h[i]) atomicAdd(&counts_i[i], h[i]);
}

// ---------------------------------------------------------------------------
// ncs, total, smoothed (1 block, 1024 threads)
// ---------------------------------------------------------------------------
__global__ __launch_bounds__(1024) void cluster_kernel(const int* __restrict__ counts_i,
                                                       const float* __restrict__ cluster_size,
                                                       float* __restrict__ out_ncs,
                                                       float* __restrict__ smoothed) {
    __shared__ float red[16];
    __shared__ float total_s;
    int k = threadIdx.x;
    float ncs = cluster_size[k] * DECAYF + OMDF * (float)counts_i[k];
    out_ncs[k] = ncs;

    float v = ncs;
#pragma unroll
    for (int off = 32; off >= 1; off >>= 1) v += __shfl_down(v, off, 64);
    if ((k & 63) == 0) red[k >> 6] = v;
    __syncthreads();
    if (k < 16) {
        float t = red[k];
#pragma unroll
        for (int off = 8; off >= 1; off >>= 1) t += __shfl_down(t, off, 16);
        if (k == 0) total_s = t;
    }
    __syncthreads();
    float total = total_s;
    smoothed[k] = (ncs + EPSF) / (total + (float)K * EPSF) * total;
}

// ---------------------------------------------------------------------------
// Segmented sum: block (k, slice) scans 1/4 of idx, queues matches, sums x.
// 4 slices -> 4x scan parallelism; partials merged with fp32 atomics.
// ---------------------------------------------------------------------------
constexpr int CH = 8192;
constexpr int SLICES = 4;

__global__ __launch_bounds__(128) void segsum_scan(const float* __restrict__ x,
                                                   const int* __restrict__ idx_i32,
                                                   float* __restrict__ embed_sum) {
    __shared__ int q[CH];
    __shared__ int qn;
    const int k = blockIdx.x;
    const int lo = blockIdx.y * (N_ROWS / SLICES);
    const int hi = lo + (N_ROWS / SLICES);
    const int tid = threadIdx.x;
    float a0 = 0.f, a1 = 0.f, a2 = 0.f, a3 = 0.f;

    for (int base = lo; base < hi; base += CH) {
        if (tid == 0) qn = 0;
        __syncthreads();
#pragma unroll 4
        for (int i = 0; i < CH / 128; ++i) {
            int row = base + i * 128 + tid;
            if (idx_i32[row] == k) {
                int p = atomicAdd(&qn, 1);
                q[p] = row;
            }
        }
        __syncthreads();
        int n = qn;
        int j = 0;
        for (; j + 4 <= n; j += 4) {
            a0 += x[(size_t)q[j + 0] * D + tid];
            a1 += x[(size_t)q[j + 1] * D + tid];
            a2 += x[(size_t)q[j + 2] * D + tid];
            a3 += x[(size_t)q[j + 3] * D + tid];
        }
        for (; j < n; ++j) a0 += x[(size_t)q[j] * D + tid];
        __syncthreads();
    }
    float esum = (a0 + a1) + (a2 + a3);
    atomicAdd(&embed_sum[(size_t)k * D + tid], esum);
}

// ---------------------------------------------------------------------------
// new_embed_avg / new_embed
// ---------------------------------------------------------------------------
__global__ __launch_bounds__(256) void embed_update_kernel(const float* __restrict__ embed_avg,
                                                           const float* __restrict__ embed_sum,
                                                           const float* __restrict__ smoothed,
                                                           float* __restrict__ out_nea,
                                                           float* __restrict__ out_ne) {
    int t = blockIdx.x * 256 + threadIdx.x;
    float4 ea = ((const float4*)embed_avg)[t];
    float4 es = ((const float4*)embed_sum)[t];
    float sm = smoothed[t >> 5];
    float4 nea;
    nea.x = ea.x * DECAYF + OMDF * es.x;
    nea.y = ea.y * DECAYF + OMDF * es.y;
    nea.z = ea.z * DECAYF + OMDF * es.z;
    nea.w = ea.w * DECAYF + OMDF * es.w;
    ((float4*)out_nea)[t] = nea;
    float4 ne;
    ne.x = nea.x / sm; ne.y = nea.y / sm; ne.z = nea.z / sm; ne.w = nea.w / sm;
    ((float4*)out_ne)[t] = ne;
}

// ---------------------------------------------------------------------------
// quantized[row] = embed[idx[row]]  (runs last: overwrites x_bf16 scratch)
// ---------------------------------------------------------------------------
__global__ __launch_bounds__(256) void gather_kernel(const float* __restrict__ embed,
                                                     const int* __restrict__ idx_i32,
                                                     float* __restrict__ quant) {
    int t = blockIdx.x * 256 + threadIdx.x;
    int row = t >> 5;
    int j = t & 31;
    int k = idx_i32[row];
    ((float4*)quant)[(size_t)row * 32 + j] = ((const float4*)embed)[(size_t)k * 32 + j];
}

// ---------------------------------------------------------------------------
extern "C" void kernel_launch(void* const* d_in, const int* in_sizes, int n_in,
                              void* d_out, int out_size, void* d_ws, size_t ws_size,
                              hipStream_t stream) {
    const float* x            = (const float*)d_in[0];
    const float* embed        = (const float*)d_in[1];
    const float* embed_avg    = (const float*)d_in[2];
    const float* cluster_size = (const float*)d_in[3];

    float* out       = (float*)d_out;
    float* out_quant = out;
    float* out_idx   = out_quant + (size_t)N_ROWS * D;
    float* out_ne    = out_idx + N_ROWS;
    float* out_ncs   = out_ne + (size_t)K * D;
    float* out_nea   = out_ncs + K;

    // x_bf16 scratch lives in the quantized output region (32 MB of 64 MB);
    // gather_kernel overwrites it at the very end.
    unsigned short* xb = (unsigned short*)out_quant;

    // workspace (~1.9 MB)
    int*   counts_i  = (int*)d_ws;                        // K
    int*   flag_cnt  = counts_i + K;                      // 1 (+3 pad)
    int*   idx_i32   = counts_i + K + 4;                  // N
    int*   flag_list = idx_i32 + N_ROWS;                  // N
    float* cnorm     = (float*)(flag_list + N_ROWS);      // K
    float* smoothed  = cnorm + K;                         // K
    float* embed_sum = smoothed + K;                      // K*D
    unsigned short* eb = (unsigned short*)(embed_sum + (size_t)K * D);  // K*D bf16

    hipMemsetAsync(counts_i, 0, (K + 4) * sizeof(int), stream);
    hipMemsetAsync(embed_sum, 0, (size_t)K * D * sizeof(float), stream);

    convert_x<<<(N_ROWS * D / 8) / 256, 256, 0, stream>>>(x, xb);
    convert_e<<<(K * D / 8) / 256, 256, 0, stream>>>(embed, eb);
    cnorm_kernel<<<(K + 255) / 256, 256, 0, stream>>>(embed, cnorm);
    mfma_dist<<<N_ROWS / 256, 256, 0, stream>>>(xb, eb, cnorm, out_idx, idx_i32,
                                                flag_cnt, flag_list);
    rescore<<<256, 256, 0, stream>>>(x, embed, cnorm, flag_cnt, flag_list, out_idx, idx_i32);
    hist_kernel<<<64, 256, 0, stream>>>(idx_i32, counts_i);
    cluster_kernel<<<1, 1024, 0, stream>>>(counts_i, cluster_size, out_ncs, smoothed);
    segsum_scan<<<dim3(K, SLICES), 128, 0, stream>>>(x, idx_i32, embed_sum);
    embed_update_kernel<<<(K * D / 4) / 256, 256, 0, stream>>>(embed_avg, embed_sum, smoothed,
                                                               out_nea, out_ne);
    gather_kernel<<<(N_ROWS * 32) / 256, 256, 0, stream>>>(embed, idx_i32, out_quant);
}

// Round 6
// 562.940 us; speedup vs baseline: 6.6181x; 1.2423x over previous
//
#include <hip/hip_runtime.h>
#include <cstdint>
#include <cstddef>

#define DECAYF 0.99f
#define OMDF   0.01f
#define EPSF   1e-5f
#define MARGIN 0.6f   // bf16 score-error 12-sigma bound; flagged rows get exact fp32 rescore

constexpr int N_ROWS = 64 * 2048;   // 131072
constexpr int D      = 128;
constexpr int K      = 1024;
constexpr int SLICES = 4;

typedef __attribute__((ext_vector_type(8))) short bf16x8;   // 8 bf16 = 4 VGPRs
typedef __attribute__((ext_vector_type(4))) float f32x4;

__device__ __forceinline__ unsigned short f2bf(float f) {
    unsigned u = __float_as_uint(f);
    u += 0x7FFFu + ((u >> 16) & 1u);   // RNE
    return (unsigned short)(u >> 16);
}

// ---------------------------------------------------------------------------
// Convert x fp32 -> bf16 (into the quantized region of d_out, overwritten last)
// ---------------------------------------------------------------------------
__global__ __launch_bounds__(256) void convert_x(const float* __restrict__ x,
                                                 unsigned short* __restrict__ xb) {
    int i = blockIdx.x * 256 + threadIdx.x;          // N*D/8 threads
    const float4* x4 = (const float4*)x;
    float4 a = x4[2 * i], b = x4[2 * i + 1];
    uint4 o;
    o.x = (unsigned)f2bf(a.x) | ((unsigned)f2bf(a.y) << 16);
    o.y = (unsigned)f2bf(a.z) | ((unsigned)f2bf(a.w) << 16);
    o.z = (unsigned)f2bf(b.x) | ((unsigned)f2bf(b.y) << 16);
    o.w = (unsigned)f2bf(b.z) | ((unsigned)f2bf(b.w) << 16);
    ((uint4*)xb)[i] = o;
}

__global__ __launch_bounds__(256) void convert_e(const float* __restrict__ e,
                                                 unsigned short* __restrict__ eb) {
    int i = blockIdx.x * 256 + threadIdx.x;          // K*D/8 threads
    const float4* e4 = (const float4*)e;
    float4 a = e4[2 * i], b = e4[2 * i + 1];
    uint4 o;
    o.x = (unsigned)f2bf(a.x) | ((unsigned)f2bf(a.y) << 16);
    o.y = (unsigned)f2bf(a.z) | ((unsigned)f2bf(a.w) << 16);
    o.z = (unsigned)f2bf(b.x) | ((unsigned)f2bf(b.y) << 16);
    o.w = (unsigned)f2bf(b.z) | ((unsigned)f2bf(b.w) << 16);
    ((uint4*)eb)[i] = o;
}

// ---------------------------------------------------------------------------
// cnorm[k] = ||embed[k]||^2 (fp32)
// ---------------------------------------------------------------------------
__global__ __launch_bounds__(256) void cnorm_kernel(const float* __restrict__ embed,
                                                    float* __restrict__ cnorm) {
    int k = blockIdx.x * 256 + threadIdx.x;
    if (k >= K) return;
    const float4* e4 = (const float4*)(embed + (size_t)k * D);
    float a0 = 0.f, a1 = 0.f, a2 = 0.f, a3 = 0.f;
#pragma unroll
    for (int i = 0; i < D / 4; ++i) {
        float4 v = e4[i];
        a0 += v.x * v.x; a1 += v.y * v.y; a2 += v.z * v.z; a3 += v.w * v.w;
    }
    cnorm[k] = (a0 + a1) + (a2 + a3);
}

// ---------------------------------------------------------------------------
// MFMA distance + approx argmax with best/best2 margin flagging.
// ---------------------------------------------------------------------------
__global__ __launch_bounds__(256) void mfma_dist(const unsigned short* __restrict__ xb,
                                                 const unsigned short* __restrict__ eb,
                                                 const float* __restrict__ cnorm,
                                                 float* __restrict__ out_idx,
                                                 int* __restrict__ idx_i32,
                                                 int* __restrict__ flag_cnt,
                                                 int* __restrict__ flag_list) {
    __shared__ float sb1[256 * 16];
    __shared__ float sb2[256 * 16];
    __shared__ float sid[256 * 16];

    const int tid = threadIdx.x;
    const int wave = tid >> 6;
    const int lane = tid & 63;
    const int l15 = lane & 15;
    const int quad = lane >> 4;
    const int rowbase = blockIdx.x * 256 + wave * 64;

    // preload A-frags: 4 sets x 4 d-chunks, 16 B contiguous each
    bf16x8 a[4][4];
#pragma unroll
    for (int s = 0; s < 4; ++s) {
        int row = rowbase + s * 16 + l15;
#pragma unroll
        for (int c = 0; c < 4; ++c)
            a[s][c] = *(const bf16x8*)(xb + (size_t)row * D + c * 32 + quad * 8);
    }

    float b1[4][4], b2[4][4], idf[4][4];
#pragma unroll
    for (int s = 0; s < 4; ++s)
#pragma unroll
        for (int r = 0; r < 4; ++r) { b1[s][r] = -3.4e38f; b2[s][r] = -3.4e38f; idf[s][r] = 0.f; }

    for (int cb = 0; cb < K; cb += 16) {
        const int code = cb + l15;
        bf16x8 bfr[4];
#pragma unroll
        for (int c = 0; c < 4; ++c)
            bfr[c] = *(const bf16x8*)(eb + (size_t)code * D + c * 32 + quad * 8);
        const float cn = cnorm[code];
        const float colf = (float)code;

#pragma unroll
        for (int s = 0; s < 4; ++s) {
            f32x4 acc = {0.f, 0.f, 0.f, 0.f};
#pragma unroll
            for (int c = 0; c < 4; ++c)
                acc = __builtin_amdgcn_mfma_f32_16x16x32_bf16(a[s][c], bfr[c], acc, 0, 0, 0);
#pragma unroll
            for (int r = 0; r < 4; ++r) {
                float sc = 2.0f * acc[r] - cn;
                float old = b1[s][r];
                b1[s][r] = fmaxf(old, sc);
                b2[s][r] = fmaxf(fminf(sc, old), b2[s][r]);
                idf[s][r] = (sc > old) ? colf : idf[s][r];
            }
        }
    }

    // dump per-lane candidates: row lr has 16 candidates (one per l15)
#pragma unroll
    for (int s = 0; s < 4; ++s)
#pragma unroll
        for (int r = 0; r < 4; ++r) {
            int lr = wave * 64 + s * 16 + quad * 4 + r;
            sb1[lr * 16 + l15] = b1[s][r];
            sb2[lr * 16 + l15] = b2[s][r];
            sid[lr * 16 + l15] = idf[s][r];
        }
    __syncthreads();

    // one thread per row: merge 16 (b1,b2,idx) candidates
    {
        float bs = sb1[tid * 16], ss = sb2[tid * 16], bi = sid[tid * 16];
#pragma unroll
        for (int j = 1; j < 16; ++j) {
            float v = sb1[tid * 16 + j];
            float w = sb2[tid * 16 + j];
            float id = sid[tid * 16 + j];
            if (v > bs) { ss = fmaxf(bs, w); bi = id; bs = v; }
            else {
                ss = fmaxf(ss, v);
                if (v == bs && id < bi) bi = id;
            }
        }
        int grow = blockIdx.x * 256 + tid;
        out_idx[grow] = bi;
        idx_i32[grow] = (int)bi;
        if (bs - ss < MARGIN) {
            int p = atomicAdd(flag_cnt, 1);
            flag_list[p] = grow;
        }
    }
}

// ---------------------------------------------------------------------------
// Exact fp32 rescore of flagged rows (tiled + indirection), grid-stride.
// ---------------------------------------------------------------------------
__global__ __launch_bounds__(256, 1) void rescore(const float* __restrict__ x,
                                                  const float* __restrict__ embed,
                                                  const float* __restrict__ cnorm,
                                                  const int* __restrict__ flag_cnt,
                                                  const int* __restrict__ flag_list,
                                                  float* __restrict__ out_idx,
                                                  int* __restrict__ idx_i32) {
    __shared__ float xs[128][132];
    __shared__ float es[128][132];

    const int tid = threadIdx.x;
    const int tx = tid & 15;
    const int ty = tid >> 4;
    const int cnt = *flag_cnt;
    const int nch = (cnt + 127) >> 7;

    for (int ch = blockIdx.x; ch < nch; ch += gridDim.x) {
        __syncthreads();
        {
            const float4* x4 = (const float4*)x;
#pragma unroll
            for (int it = 0; it < 16; ++it) {
                int idx = it * 256 + tid;
                int slot = idx >> 5, c4 = idx & 31;
                int fi = ch * 128 + slot;
                int grow = flag_list[fi < cnt ? fi : cnt - 1];
                float4 v = x4[(size_t)grow * 32 + c4];
                *(float4*)&xs[slot][c4 * 4] = v;
            }
        }

        float best[8];
        int bidx[8];
#pragma unroll
        for (int r = 0; r < 8; ++r) { best[r] = -3.4e38f; bidx[r] = 0; }

        const float4* e4 = (const float4*)embed;
        for (int t = 0; t < 8; ++t) {
            __syncthreads();
            {
                const size_t base4 = (size_t)t * 128 * 32;
#pragma unroll
                for (int it = 0; it < 16; ++it) {
                    int idx = it * 256 + tid;
                    int row = idx >> 5, c4 = idx & 31;
                    float4 v = e4[base4 + idx];
                    *(float4*)&es[row][c4 * 4] = v;
                }
            }
            float cn[8];
#pragma unroll
            for (int c = 0; c < 8; ++c) cn[c] = cnorm[t * 128 + tx + 16 * c];
            __syncthreads();

            float acc[8][8];
#pragma unroll
            for (int r = 0; r < 8; ++r)
#pragma unroll
                for (int c = 0; c < 8; ++c) acc[r][c] = 0.f;

#pragma unroll 2
            for (int d4 = 0; d4 < 32; ++d4) {
                float4 av[8], bv[8];
#pragma unroll
                for (int r = 0; r < 8; ++r) av[r] = *(const float4*)&xs[ty + 16 * r][4 * d4];
#pragma unroll
                for (int c = 0; c < 8; ++c) bv[c] = *(const float4*)&es[tx + 16 * c][4 * d4];
#pragma unroll
                for (int r = 0; r < 8; ++r)
#pragma unroll
                    for (int c = 0; c < 8; ++c) {
                        acc[r][c] = fmaf(av[r].x, bv[c].x, acc[r][c]);
                        acc[r][c] = fmaf(av[r].y, bv[c].y, acc[r][c]);
                        acc[r][c] = fmaf(av[r].z, bv[c].z, acc[r][c]);
                        acc[r][c] = fmaf(av[r].w, bv[c].w, acc[r][c]);
                    }
            }

#pragma unroll
            for (int r = 0; r < 8; ++r)
#pragma unroll
                for (int c = 0; c < 8; ++c) {
                    float s = 2.0f * acc[r][c] - cn[c];
                    if (s > best[r]) { best[r] = s; bidx[r] = t * 128 + tx + 16 * c; }
                }
        }

        __syncthreads();
        float* sbest = &es[0][0];
        int*   sidx  = (int*)&xs[0][0];
#pragma unroll
        for (int r = 0; r < 8; ++r) {
            int row = ty + 16 * r;
            sbest[row * 16 + tx] = best[r];
            sidx[row * 16 + tx] = bidx[r];
        }
        __syncthreads();
        if (tid < 128) {
            float bs = sbest[tid * 16];
            int bi = sidx[tid * 16];
#pragma unroll
            for (int j = 1; j < 16; ++j) {
                float s = sbest[tid * 16 + j];
                int id = sidx[tid * 16 + j];
                if (s > bs || (s == bs && id < bi)) { bs = s; bi = id; }
            }
            int fi = ch * 128 + tid;
            if (fi < cnt) {
                int grow = flag_list[fi];
                out_idx[grow] = (float)bi;
                idx_i32[grow] = bi;
            }
        }
    }
}

// ---------------------------------------------------------------------------
// Histogram of final indices (LDS-privatized)
// ---------------------------------------------------------------------------
__global__ __launch_bounds__(256) void hist_kernel(const int* __restrict__ idx_i32,
                                                   int* __restrict__ counts_i) {
    __shared__ int h[K];
    for (int i = threadIdx.x; i < K; i += 256) h[i] = 0;
    __syncthreads();
    for (int row = blockIdx.x * 256 + threadIdx.x; row < N_ROWS; row += gridDim.x * 256)
        atomicAdd(&h[idx_i32[row]], 1);
    __syncthreads();
    for (int i = threadIdx.x; i < K; i += 256)
        if (h[i]) atomicAdd(&counts_i[i], h[i]);
}

// ---------------------------------------------------------------------------
// scan counts -> offsets/cursor; ncs, total, smoothed (1 block, 1024 thr)
// ---------------------------------------------------------------------------
__global__ __launch_bounds__(1024) void scan_cluster_kernel(const int* __restrict__ counts_i,
                                                            const float* __restrict__ cluster_size,
                                                            int* __restrict__ offsets,
                                                            int* __restrict__ cursor,
                                                            float* __restrict__ out_ncs,
                                                            float* __restrict__ smoothed) {
    __shared__ int s[1024];
    __shared__ float red[16];
    __shared__ float total_s;
    int k = threadIdx.x;
    int c = counts_i[k];
    s[k] = c;
    __syncthreads();
    for (int off = 1; off < 1024; off <<= 1) {
        int v = (k >= off) ? s[k - off] : 0;
        __syncthreads();
        s[k] += v;
        __syncthreads();
    }
    int offx = s[k] - c;   // exclusive
    offsets[k] = offx;
    cursor[k] = offx;

    float ncs = cluster_size[k] * DECAYF + OMDF * (float)c;
    out_ncs[k] = ncs;

    float v = ncs;
#pragma unroll
    for (int off = 32; off >= 1; off >>= 1) v += __shfl_down(v, off, 64);
    if ((k & 63) == 0) red[k >> 6] = v;
    __syncthreads();
    if (k < 16) {
        float t = red[k];
#pragma unroll
        for (int off = 8; off >= 1; off >>= 1) t += __shfl_down(t, off, 16);
        if (k == 0) total_s = t;
    }
    __syncthreads();
    float total = total_s;
    smoothed[k] = (ncs + EPSF) / (total + (float)K * EPSF) * total;
}

// ---------------------------------------------------------------------------
// scatter row ids into per-code segments (cursor atomics, ~128-way avg)
// ---------------------------------------------------------------------------
__global__ __launch_bounds__(256) void scatter_kernel(const int* __restrict__ idx_i32,
                                                      int* __restrict__ cursor,
                                                      int* __restrict__ rowlist) {
    int row = blockIdx.x * 256 + threadIdx.x;
    int code = idx_i32[row];
    int pos = atomicAdd(&cursor[code], 1);
    rowlist[pos] = row;
}

// ---------------------------------------------------------------------------
// Segmented gather-sum: block (k, slice); no LDS -> 32 waves/CU latency hiding.
// Partial sums merged into embed_sum via fp32 atomics (512K atomics total).
// ---------------------------------------------------------------------------
__global__ __launch_bounds__(128) void segsum_gather(const float* __restrict__ x,
                                                     const int* __restrict__ offsets,
                                                     const int* __restrict__ counts_i,
                                                     const int* __restrict__ rowlist,
                                                     float* __restrict__ embed_sum) {
    const int k = blockIdx.x;
    const int sl = blockIdx.y;
    const int d = threadIdx.x;
    const int start = offsets[k];
    const int cnt = counts_i[k];
    const int len = (cnt + SLICES - 1) / SLICES;
    const int lo = sl * len;
    const int hi = min(lo + len, cnt);

    float a0 = 0.f, a1 = 0.f, a2 = 0.f, a3 = 0.f;
    int i = lo;
    for (; i + 4 <= hi; i += 4) {
        int r0 = rowlist[start + i + 0];
        int r1 = rowlist[start + i + 1];
        int r2 = rowlist[start + i + 2];
        int r3 = rowlist[start + i + 3];
        a0 += x[(size_t)r0 * D + d];
        a1 += x[(size_t)r1 * D + d];
        a2 += x[(size_t)r2 * D + d];
        a3 += x[(size_t)r3 * D + d];
    }
    for (; i < hi; ++i) a0 += x[(size_t)rowlist[start + i] * D + d];
    float part = (a0 + a1) + (a2 + a3);
    if (part != 0.f) atomicAdd(&embed_sum[(size_t)k * D + d], part);
}

// ---------------------------------------------------------------------------
// new_embed_avg / new_embed
// ---------------------------------------------------------------------------
__global__ __launch_bounds__(256) void embed_update_kernel(const float* __restrict__ embed_avg,
                                                           const float* __restrict__ embed_sum,
                                                           const float* __restrict__ smoothed,
                                                           float* __restrict__ out_nea,
                                                           float* __restrict__ out_ne) {
    int t = blockIdx.x * 256 + threadIdx.x;
    float4 ea = ((const float4*)embed_avg)[t];
    float4 es = ((const float4*)embed_sum)[t];
    float sm = smoothed[t >> 5];
    float4 nea;
    nea.x = ea.x * DECAYF + OMDF * es.x;
    nea.y = ea.y * DECAYF + OMDF * es.y;
    nea.z = ea.z * DECAYF + OMDF * es.z;
    nea.w = ea.w * DECAYF + OMDF * es.w;
    ((float4*)out_nea)[t] = nea;
    float4 ne;
    ne.x = nea.x / sm; ne.y = nea.y / sm; ne.z = nea.z / sm; ne.w = nea.w / sm;
    ((float4*)out_ne)[t] = ne;
}

// ---------------------------------------------------------------------------
// quantized[row] = embed[idx[row]]  (runs last: overwrites x_bf16 scratch)
// ---------------------------------------------------------------------------
__global__ __launch_bounds__(256) void gather_kernel(const float* __restrict__ embed,
                                                     const int* __restrict__ idx_i32,
                                                     float* __restrict__ quant) {
    int t = blockIdx.x * 256 + threadIdx.x;
    int row = t >> 5;
    int j = t & 31;
    int k = idx_i32[row];
    ((float4*)quant)[(size_t)row * 32 + j] = ((const float4*)embed)[(size_t)k * 32 + j];
}

// ---------------------------------------------------------------------------
extern "C" void kernel_launch(void* const* d_in, const int* in_sizes, int n_in,
                              void* d_out, int out_size, void* d_ws, size_t ws_size,
                              hipStream_t stream) {
    const float* x            = (const float*)d_in[0];
    const float* embed        = (const float*)d_in[1];
    const float* embed_avg    = (const float*)d_in[2];
    const float* cluster_size = (const float*)d_in[3];

    float* out       = (float*)d_out;
    float* out_quant = out;
    float* out_idx   = out_quant + (size_t)N_ROWS * D;
    float* out_ne    = out_idx + N_ROWS;
    float* out_ncs   = out_ne + (size_t)K * D;
    float* out_nea   = out_ncs + K;

    // x_bf16 scratch lives in the quantized output region (overwritten last)
    unsigned short* xb = (unsigned short*)out_quant;

    // workspace (~2.4 MB)
    int*   counts_i  = (int*)d_ws;                        // K
    int*   flag_cnt  = counts_i + K;                      // 1 (+3 pad)
    int*   idx_i32   = counts_i + K + 4;                  // N
    int*   flag_list = idx_i32 + N_ROWS;                  // N
    int*   offsets   = flag_list + N_ROWS;                // K
    int*   cursor    = offsets + K;                       // K
    int*   rowlist   = cursor + K;                        // N
    float* cnorm     = (float*)(rowlist + N_ROWS);        // K
    float* smoothed  = cnorm + K;                         // K
    float* embed_sum = smoothed + K;                      // K*D
    unsigned short* eb = (unsigned short*)(embed_sum + (size_t)K * D);  // K*D bf16

    hipMemsetAsync(counts_i, 0, (K + 4) * sizeof(int), stream);
    hipMemsetAsync(embed_sum, 0, (size_t)K * D * sizeof(float), stream);

    convert_x<<<(N_ROWS * D / 8) / 256, 256, 0, stream>>>(x, xb);
    convert_e<<<(K * D / 8) / 256, 256, 0, stream>>>(embed, eb);
    cnorm_kernel<<<(K + 255) / 256, 256, 0, stream>>>(embed, cnorm);
    mfma_dist<<<N_ROWS / 256, 256, 0, stream>>>(xb, eb, cnorm, out_idx, idx_i32,
                                                flag_cnt, flag_list);
    rescore<<<256, 256, 0, stream>>>(x, embed, cnorm, flag_cnt, flag_list, out_idx, idx_i32);
    hist_kernel<<<64, 256, 0, stream>>>(idx_i32, counts_i);
    scan_cluster_kernel<<<1, 1024, 0, stream>>>(counts_i, cluster_size, offsets, cursor,
                                                out_ncs, smoothed);
    scatter_kernel<<<N_ROWS / 256, 256, 0, stream>>>(idx_i32, cursor, rowlist);
    segsum_gather<<<dim3(K, SLICES), 128, 0, stream>>>(x, offsets, counts_i, rowlist, embed_sum);
    embed_update_kernel<<<(K * D / 4) / 256, 256, 0, stream>>>(embed_avg, embed_sum, smoothed,
                                                               out_nea, out_ne);
    gather_kernel<<<(N_ROWS * 32) / 256, 256, 0, stream>>>(embed, idx_i32, out_quant);
}